// Round 11
// baseline (176.274 us; speedup 1.0000x reference)
//
#include <hip/hip_runtime.h>
#include <hip/hip_bf16.h>

typedef __bf16 bf16x8 __attribute__((ext_vector_type(8)));
typedef float f32x4 __attribute__((ext_vector_type(4)));
typedef __hip_bfloat16 bf16;

#define B_ 4
#define S_ 2048
#define D_ 1024
#define H_ 16
#define HD_ 64

__device__ __forceinline__ void gload16(const bf16* g, bf16* l) {
  __builtin_amdgcn_global_load_lds(
      (const __attribute__((address_space(1))) unsigned int*)g,
      (__attribute__((address_space(3))) unsigned int*)l, 16, 0, 0);
}

// ---------------------------------------------------------------- cvt f32->bf16 (fused x, w_qkv, w_out)
#define NX_ (B_ * S_ * D_)
#define NW1_ (3 * D_ * D_)
#define NW2_ (D_ * D_)
__global__ __launch_bounds__(256) void k_cvt3(const float* __restrict__ x,
                                              const float* __restrict__ w1,
                                              const float* __restrict__ w2,
                                              bf16* __restrict__ ox,
                                              bf16* __restrict__ o1,
                                              bf16* __restrict__ o2) {
  int i = (blockIdx.x * 256 + threadIdx.x) * 4;
  const float* in;
  bf16* out;
  if (i < NX_) {
    in = x; out = ox;
  } else if (i < NX_ + NW1_) {
    in = w1; out = o1; i -= NX_;
  } else {
    in = w2; out = o2; i -= NX_ + NW1_;
  }
  float4 v = *reinterpret_cast<const float4*>(in + i);
  alignas(8) bf16 t[4];
  t[0] = __float2bfloat16(v.x);
  t[1] = __float2bfloat16(v.y);
  t[2] = __float2bfloat16(v.z);
  t[3] = __float2bfloat16(v.w);
  *reinterpret_cast<uint2*>(out + i) = *reinterpret_cast<uint2*>(t);
}

// ---------------------------------------------------------------- QKV GEMM
// BM=128 x BN=256, BK=64, 512 thr (8 waves 2Mx4N). Counted vmcnt + raw
// s_barrier (T3+T4): per iter, vmcnt(6) keeps next tile's 6 loads in flight
// across the barrier; stage kt+2 issued into the buffer freed by barrier#2.
// Both-sides XOR swizzle (R10-validated). LDS 96KB -> 1 block/CU, grid 768
// = 3 exact rounds. Q gets RoPE * 0.125*log2(e); K RoPE; V -> [bh][d][s].
__global__ __launch_bounds__(512) void k_qkv(const bf16* __restrict__ X,
                                             const bf16* __restrict__ W,
                                             bf16* __restrict__ Qw,
                                             bf16* __restrict__ Kw,
                                             bf16* __restrict__ Vtw) {
  __shared__ bf16 Al[2][128 * 64];  // 32 KB
  __shared__ bf16 Bl[2][256 * 64];  // 64 KB
  const int tid = threadIdx.x;
  const int wid = tid >> 6, lane = tid & 63, col = lane & 15, g = lane >> 4;
  const int wr = wid >> 2, wc = wid & 3;
  const int m0 = blockIdx.x * 128, n0 = blockIdx.y * 256;
  const int srow = tid >> 3;                         // 0..63
  const int scol = (tid & 7) * 8;
  const int csrc = scol ^ ((srow & 7) * 8);          // pre-swizzled source col
  const bf16* ga = X + (size_t)(m0 + srow) * 1024 + csrc;
  const bf16* gb = W + (size_t)(n0 + srow) * 1024 + csrc;
  const int ldst = srow * 64 + scol;                 // linear LDS dest
  const int rsw = (col & 7) * 8;
  f32x4 acc[4][4] = {};
#define QKV_STAGE(buf, k0)                                   \
  do {                                                       \
    gload16(ga + (k0), &Al[buf][ldst]);                      \
    gload16(ga + (k0) + 64 * 1024, &Al[buf][ldst + 4096]);   \
    gload16(gb + (k0), &Bl[buf][ldst]);                      \
    gload16(gb + (k0) + 64 * 1024, &Bl[buf][ldst + 4096]);   \
    gload16(gb + (k0) + 128 * 1024, &Bl[buf][ldst + 8192]);  \
    gload16(gb + (k0) + 192 * 1024, &Bl[buf][ldst + 12288]); \
  } while (0)
  QKV_STAGE(0, 0);
  QKV_STAGE(1, 64);
  for (int kt = 0; kt < 16; ++kt) {
    const int c = kt & 1;
    if (kt < 15)
      asm volatile("s_waitcnt vmcnt(6)" ::: "memory");
    else
      asm volatile("s_waitcnt vmcnt(0)" ::: "memory");
    __builtin_amdgcn_s_barrier();  // tile kt visible to all waves
    const bf16* Ac = Al[c];
    const bf16* Bc = Bl[c];
#pragma unroll
    for (int kk = 0; kk < 2; ++kk) {
      const int ce = (kk * 32 + g * 8) ^ rsw;
      bf16x8 af[4], bfr[4];
#pragma unroll
      for (int m = 0; m < 4; ++m)
        af[m] = *reinterpret_cast<const bf16x8*>(&Ac[(wr * 64 + m * 16 + col) * 64 + ce]);
#pragma unroll
      for (int n = 0; n < 4; ++n)
        bfr[n] =
            *reinterpret_cast<const bf16x8*>(&Bc[(wc * 64 + n * 16 + col) * 64 + ce]);
      __builtin_amdgcn_s_setprio(1);
#pragma unroll
      for (int m = 0; m < 4; ++m)
#pragma unroll
        for (int n = 0; n < 4; ++n)
          acc[m][n] =
              __builtin_amdgcn_mfma_f32_16x16x32_bf16(af[m], bfr[n], acc[m][n], 0, 0, 0);
      __builtin_amdgcn_s_setprio(0);
    }
    __builtin_amdgcn_s_barrier();  // all waves done reading buf c
    if (kt + 2 < 16) QKV_STAGE(c, (kt + 2) * 64);
  }
#undef QKV_STAGE
  const int e0 = n0 + wc * 64;
  const int which = e0 >> 10;
  const int h = (e0 >> 6) & 15;
  if (which == 2) {
#pragma unroll
    for (int m = 0; m < 4; ++m) {
      int mg = m0 + wr * 64 + m * 16 + g * 4;
      int b = mg >> 11, s = mg & 2047;
#pragma unroll
      for (int n = 0; n < 4; ++n) {
        int d = n * 16 + col;
        alignas(8) bf16 t[4];
#pragma unroll
        for (int r = 0; r < 4; ++r) t[r] = __float2bfloat16(acc[m][n][r]);
        *reinterpret_cast<uint2*>(&Vtw[((size_t)((b * 16 + h) * 64 + d) << 11) + s]) =
            *reinterpret_cast<uint2*>(t);
      }
    }
  } else {
    bf16* dst = which ? Kw : Qw;
    const float scale = which ? 1.0f : 0.18033688011112042f;  // 0.125*log2(e)
    const float fexp = -2.0f * 13.287712379549449f / 64.0f;
#pragma unroll
    for (int i = 0; i < 2; ++i) {
      int dlo = i * 16 + col;
      float invf = exp2f(fexp * (float)dlo);
#pragma unroll
      for (int m = 0; m < 4; ++m) {
        int mg = m0 + wr * 64 + m * 16 + g * 4;
        int b = mg >> 11;
        size_t rb = (size_t)(b * 16 + h) << 11;
#pragma unroll
        for (int r = 0; r < 4; ++r) {
          int s = (mg + r) & 2047;
          float sn, cs;
          __sincosf((float)s * invf, &sn, &cs);
          float lo = acc[m][i][r] * scale, hi = acc[m][i + 2][r] * scale;
          dst[((rb + s) << 6) + dlo] = __float2bfloat16(lo * cs - hi * sn);
          dst[((rb + s) << 6) + dlo + 32] = __float2bfloat16(hi * cs + lo * sn);
        }
      }
    }
  }
}

// ---------------------------------------------------------------- flash attention (frozen, R10)
__global__ __launch_bounds__(512) void k_attn(const bf16* __restrict__ Q,
                                              const bf16* __restrict__ K,
                                              const bf16* __restrict__ Vt,
                                              bf16* __restrict__ AO) {
  __shared__ bf16 QPl[128][72];  // Q staging, then P buffer (wave-private rows)
  __shared__ bf16 Kl[64][72];
  __shared__ bf16 Vl[64][72];  // [d][key]
  const int tid = threadIdx.x;
  const int wave = tid >> 6, lane = tid & 63, col = lane & 15, g = lane >> 4;
  const int bh = blockIdx.x;
  const size_t base = (size_t)bh << 17;
  const int r0 = tid >> 3, c0 = (tid & 7) * 8;  // r0: 0..63
  const int b = bh >> 4, h = bh & 15;
  // y -> qt mapping: quartets {y,y+4,y+8,y+12} sum to 30 => equal per-CU work
  const int yy = blockIdx.y, a = yy >> 2, r_ = yy & 3;
  const int qt = (a == 0) ? (15 - r_) : (a == 1) ? (8 + (r_ ^ 2)) : (a == 2) ? (4 + (r_ ^ 1)) : r_;
  const int q0 = qt * 128;
  *reinterpret_cast<int4*>(&QPl[r0][c0]) =
      *reinterpret_cast<const int4*>(&Q[base + (size_t)(q0 + r0) * 64 + c0]);
  *reinterpret_cast<int4*>(&QPl[r0 + 64][c0]) =
      *reinterpret_cast<const int4*>(&Q[base + (size_t)(q0 + r0 + 64) * 64 + c0]);
  const int ktlim = 2 * qt + 1;
  const int ktmax = (q0 + wave * 16 + 15) >> 6;
  int4 kr = *reinterpret_cast<const int4*>(&K[base + (size_t)r0 * 64 + c0]);
  int4 vr = *reinterpret_cast<const int4*>(&Vt[base + (size_t)r0 * 2048 + c0]);
  *reinterpret_cast<int4*>(&Kl[r0][c0]) = kr;
  *reinterpret_cast<int4*>(&Vl[r0][c0]) = vr;
  kr = *reinterpret_cast<const int4*>(&K[base + (size_t)(64 + r0) * 64 + c0]);
  vr = *reinterpret_cast<const int4*>(&Vt[base + (size_t)r0 * 2048 + 64 + c0]);
  __syncthreads();
  bf16x8 qf[2];
#pragma unroll
  for (int kk = 0; kk < 2; ++kk)
    qf[kk] = *reinterpret_cast<const bf16x8*>(&QPl[wave * 16 + col][g * 8 + kk * 32]);
  float l_s = 0.0f;
  f32x4 o[4] = {};
  for (int kt = 0; kt <= ktlim; ++kt) {
    const int k0 = kt * 64;
    if (kt <= ktmax) {
      const int q = q0 + wave * 16 + col;
      const bool needmask = (k0 + 63 > q0 + wave * 16);  // wave-uniform
      __builtin_amdgcn_s_setprio(1);
#pragma unroll
      for (int n = 0; n < 4; ++n) {
        f32x4 s = {};
#pragma unroll
        for (int kk = 0; kk < 2; ++kk) {
          bf16x8 kf =
              *reinterpret_cast<const bf16x8*>(&Kl[n * 16 + col][g * 8 + kk * 32]);
          s = __builtin_amdgcn_mfma_f32_16x16x32_bf16(kf, qf[kk], s, 0, 0, 0);
        }
        if (needmask) {
#pragma unroll
          for (int r = 0; r < 4; ++r)
            if (k0 + n * 16 + g * 4 + r > q) s[r] = -3e38f;
        }
        alignas(8) bf16 t[4];
#pragma unroll
        for (int r = 0; r < 4; ++r) {
          float p = exp2f(s[r]);
          l_s += p;
          t[r] = __float2bfloat16(p);
        }
        *reinterpret_cast<uint2*>(&QPl[wave * 16 + col][n * 16 + g * 4]) =
            *reinterpret_cast<uint2*>(t);
      }
#pragma unroll
      for (int kk = 0; kk < 2; ++kk) {
        bf16x8 pf =
            *reinterpret_cast<const bf16x8*>(&QPl[wave * 16 + col][g * 8 + kk * 32]);
#pragma unroll
        for (int n2 = 0; n2 < 4; ++n2) {
          bf16x8 vf =
              *reinterpret_cast<const bf16x8*>(&Vl[n2 * 16 + col][g * 8 + kk * 32]);
          o[n2] = __builtin_amdgcn_mfma_f32_16x16x32_bf16(pf, vf, o[n2], 0, 0, 0);
        }
      }
      __builtin_amdgcn_s_setprio(0);
    }
    __syncthreads();
    if (kt < ktlim) {
      *reinterpret_cast<int4*>(&Kl[r0][c0]) = kr;
      *reinterpret_cast<int4*>(&Vl[r0][c0]) = vr;
      if (kt + 2 <= ktlim) {
        const int k2 = k0 + 128;
        kr = *reinterpret_cast<const int4*>(&K[base + (size_t)(k2 + r0) * 64 + c0]);
        vr = *reinterpret_cast<const int4*>(&Vt[base + (size_t)r0 * 2048 + k2 + c0]);
      }
      __syncthreads();
    }
  }
  l_s += __shfl_xor(l_s, 16);
  l_s += __shfl_xor(l_s, 32);
#pragma unroll
  for (int r = 0; r < 4; ++r) {
    float inv = 1.0f / __shfl(l_s, (lane & 48) | (g * 4 + r));
    int s = q0 + wave * 16 + g * 4 + r;
#pragma unroll
    for (int n2 = 0; n2 < 4; ++n2)
      AO[((size_t)(b * 2048 + s) << 10) + h * 64 + n2 * 16 + col] =
          __float2bfloat16(o[n2][r] * inv);
  }
}

// ---------------------------------------------------------------- out projection
// Same BM=128 x BN=256 counted-vmcnt template. Grid 64x4 = 256 blocks = 1 round.
__global__ __launch_bounds__(512) void k_outproj(const bf16* __restrict__ A,
                                                 const bf16* __restrict__ W,
                                                 float* __restrict__ OUT) {
  __shared__ bf16 Al[2][128 * 64];
  __shared__ bf16 Bl[2][256 * 64];
  const int tid = threadIdx.x;
  const int wid = tid >> 6, lane = tid & 63, col = lane & 15, g = lane >> 4;
  const int wr = wid >> 2, wc = wid & 3;
  const int m0 = blockIdx.x * 128, n0 = blockIdx.y * 256;
  const int srow = tid >> 3;
  const int scol = (tid & 7) * 8;
  const int csrc = scol ^ ((srow & 7) * 8);
  const bf16* ga = A + (size_t)(m0 + srow) * 1024 + csrc;
  const bf16* gb = W + (size_t)(n0 + srow) * 1024 + csrc;
  const int ldst = srow * 64 + scol;
  const int rsw = (col & 7) * 8;
  f32x4 acc[4][4] = {};
#define OP_STAGE(buf, k0)                                    \
  do {                                                       \
    gload16(ga + (k0), &Al[buf][ldst]);                      \
    gload16(ga + (k0) + 64 * 1024, &Al[buf][ldst + 4096]);   \
    gload16(gb + (k0), &Bl[buf][ldst]);                      \
    gload16(gb + (k0) + 64 * 1024, &Bl[buf][ldst + 4096]);   \
    gload16(gb + (k0) + 128 * 1024, &Bl[buf][ldst + 8192]);  \
    gload16(gb + (k0) + 192 * 1024, &Bl[buf][ldst + 12288]); \
  } while (0)
  OP_STAGE(0, 0);
  OP_STAGE(1, 64);
  for (int kt = 0; kt < 16; ++kt) {
    const int c = kt & 1;
    if (kt < 15)
      asm volatile("s_waitcnt vmcnt(6)" ::: "memory");
    else
      asm volatile("s_waitcnt vmcnt(0)" ::: "memory");
    __builtin_amdgcn_s_barrier();
    const bf16* Ac = Al[c];
    const bf16* Bc = Bl[c];
#pragma unroll
    for (int kk = 0; kk < 2; ++kk) {
      const int ce = (kk * 32 + g * 8) ^ rsw;
      bf16x8 af[4], bfr[4];
#pragma unroll
      for (int m = 0; m < 4; ++m)
        af[m] = *reinterpret_cast<const bf16x8*>(&Ac[(wr * 64 + m * 16 + col) * 64 + ce]);
#pragma unroll
      for (int n = 0; n < 4; ++n)
        bfr[n] =
            *reinterpret_cast<const bf16x8*>(&Bc[(wc * 64 + n * 16 + col) * 64 + ce]);
      __builtin_amdgcn_s_setprio(1);
#pragma unroll
      for (int m = 0; m < 4; ++m)
#pragma unroll
        for (int n = 0; n < 4; ++n)
          acc[m][n] =
              __builtin_amdgcn_mfma_f32_16x16x32_bf16(af[m], bfr[n], acc[m][n], 0, 0, 0);
      __builtin_amdgcn_s_setprio(0);
    }
    __builtin_amdgcn_s_barrier();
    if (kt + 2 < 16) OP_STAGE(c, (kt + 2) * 64);
  }
#undef OP_STAGE
#pragma unroll
  for (int m = 0; m < 4; ++m)
#pragma unroll
    for (int n = 0; n < 4; ++n)
#pragma unroll
      for (int r = 0; r < 4; ++r)
        OUT[(size_t)(m0 + wr * 64 + m * 16 + g * 4 + r) * 1024 + n0 + wc * 64 + n * 16 +
            col] = acc[m][n][r];
}

// ---------------------------------------------------------------- launcher
extern "C" void kernel_launch(void* const* d_in, const int* in_sizes, int n_in,
                              void* d_out, int out_size, void* d_ws, size_t ws_size,
                              hipStream_t stream) {
  const float* x = (const float*)d_in[0];
  const float* wqkv = (const float*)d_in[1];
  const float* wout = (const float*)d_in[2];
  float* out = (float*)d_out;

  char* ws = (char*)d_ws;
  const size_t SZ_X = (size_t)B_ * S_ * D_ * 2;
  const size_t SZ_WQKV = (size_t)3 * D_ * D_ * 2;
  const size_t SZ_WOUT = (size_t)D_ * D_ * 2;
  const size_t SZ_T = (size_t)B_ * H_ * S_ * HD_ * 2;
  bf16* xb = (bf16*)(ws);
  bf16* wqkvb = (bf16*)(ws + SZ_X);
  bf16* woutb = (bf16*)(ws + SZ_X + SZ_WQKV);
  bf16* qws = (bf16*)(ws + SZ_X + SZ_WQKV + SZ_WOUT);
  bf16* kws = (bf16*)(ws + SZ_X + SZ_WQKV + SZ_WOUT + SZ_T);
  bf16* vtws = (bf16*)(ws + SZ_X + SZ_WQKV + SZ_WOUT + 2 * SZ_T);
  bf16* aob = (bf16*)(ws + SZ_X + SZ_WQKV + SZ_WOUT + 3 * SZ_T);

  const int NTOT4 = (NX_ + NW1_ + NW2_) / 4;
  k_cvt3<<<NTOT4 / 256, 256, 0, stream>>>(x, wqkv, wout, xb, wqkvb, woutb);

  k_qkv<<<dim3(64, 12), 512, 0, stream>>>(xb, wqkvb, qws, kws, vtws);
  k_attn<<<dim3(B_ * H_, 16), 512, 0, stream>>>(qws, kws, vtws, aob);
  k_outproj<<<dim3(64, 4), 512, 0, stream>>>(aob, woutb, out);
}

// Round 12
// 163.122 us; speedup vs baseline: 1.0806x; 1.0806x over previous
//
#include <hip/hip_runtime.h>
#include <hip/hip_bf16.h>

typedef __bf16 bf16x8 __attribute__((ext_vector_type(8)));
typedef float f32x4 __attribute__((ext_vector_type(4)));
typedef __hip_bfloat16 bf16;

#define B_ 4
#define S_ 2048
#define D_ 1024
#define H_ 16
#define HD_ 64

__device__ __forceinline__ void gload16(const bf16* g, bf16* l) {
  __builtin_amdgcn_global_load_lds(
      (const __attribute__((address_space(1))) unsigned int*)g,
      (__attribute__((address_space(3))) unsigned int*)l, 16, 0, 0);
}

// ---------------------------------------------------------------- cvt f32->bf16 (fused x, w_qkv, w_out)
#define NX_ (B_ * S_ * D_)
#define NW1_ (3 * D_ * D_)
#define NW2_ (D_ * D_)
__global__ __launch_bounds__(256) void k_cvt3(const float* __restrict__ x,
                                              const float* __restrict__ w1,
                                              const float* __restrict__ w2,
                                              bf16* __restrict__ ox,
                                              bf16* __restrict__ o1,
                                              bf16* __restrict__ o2) {
  int i = (blockIdx.x * 256 + threadIdx.x) * 4;
  const float* in;
  bf16* out;
  if (i < NX_) {
    in = x; out = ox;
  } else if (i < NX_ + NW1_) {
    in = w1; out = o1; i -= NX_;
  } else {
    in = w2; out = o2; i -= NX_ + NW1_;
  }
  float4 v = *reinterpret_cast<const float4*>(in + i);
  alignas(8) bf16 t[4];
  t[0] = __float2bfloat16(v.x);
  t[1] = __float2bfloat16(v.y);
  t[2] = __float2bfloat16(v.z);
  t[3] = __float2bfloat16(v.w);
  *reinterpret_cast<uint2*>(out + i) = *reinterpret_cast<uint2*>(t);
}

// ---------------------------------------------------------------- QKV GEMM (R10: 128x128, BK=64, T2 swizzle)
__global__ __launch_bounds__(256) void k_qkv(const bf16* __restrict__ X,
                                             const bf16* __restrict__ W,
                                             bf16* __restrict__ Qw,
                                             bf16* __restrict__ Kw,
                                             bf16* __restrict__ Vtw) {
  __shared__ bf16 Al[128 * 64];
  __shared__ bf16 Bl[128 * 64];
  const int tid = threadIdx.x;
  const int wave = tid >> 6, lane = tid & 63, col = lane & 15, g = lane >> 4;
  const int m0 = blockIdx.x * 128, n0 = blockIdx.y * 128;
  const int wrow = (wave >> 1) * 64, wcol = (wave & 1) * 64;
  const int row8 = tid >> 3;
  const int cel = ((tid & 7) * 8) ^ ((row8 & 7) * 8);
  const bf16* ga = X + (size_t)(m0 + row8) * 1024 + cel;
  const bf16* gb = W + (size_t)(n0 + row8) * 1024 + cel;
  bf16* la = Al + tid * 8;
  bf16* lb = Bl + tid * 8;
  const int rsw = (col & 7) * 8;
  f32x4 acc[4][4] = {};
  for (int k0 = 0; k0 < 1024; k0 += 64) {
    __syncthreads();
#pragma unroll
    for (int i = 0; i < 4; ++i) {
      gload16(ga + k0 + i * 32 * 1024, la + i * 2048);
      gload16(gb + k0 + i * 32 * 1024, lb + i * 2048);
    }
    __syncthreads();
#pragma unroll
    for (int kk = 0; kk < 2; ++kk) {
      const int ce = (kk * 32 + g * 8) ^ rsw;
      bf16x8 af[4], bfr[4];
#pragma unroll
      for (int m = 0; m < 4; ++m)
        af[m] = *reinterpret_cast<const bf16x8*>(&Al[(wrow + m * 16 + col) * 64 + ce]);
#pragma unroll
      for (int n = 0; n < 4; ++n)
        bfr[n] = *reinterpret_cast<const bf16x8*>(&Bl[(wcol + n * 16 + col) * 64 + ce]);
#pragma unroll
      for (int m = 0; m < 4; ++m)
#pragma unroll
        for (int n = 0; n < 4; ++n)
          acc[m][n] =
              __builtin_amdgcn_mfma_f32_16x16x32_bf16(af[m], bfr[n], acc[m][n], 0, 0, 0);
    }
  }
  const int e0 = n0 + wcol;
  const int which = e0 >> 10;
  const int h = (e0 >> 6) & 15;
  if (which == 2) {
#pragma unroll
    for (int m = 0; m < 4; ++m) {
      int mg = m0 + wrow + m * 16 + g * 4;
      int b = mg >> 11, s = mg & 2047;
#pragma unroll
      for (int n = 0; n < 4; ++n) {
        int d = n * 16 + col;
        alignas(8) bf16 t[4];
#pragma unroll
        for (int r = 0; r < 4; ++r) t[r] = __float2bfloat16(acc[m][n][r]);
        *reinterpret_cast<uint2*>(&Vtw[((size_t)((b * 16 + h) * 64 + d) << 11) + s]) =
            *reinterpret_cast<uint2*>(t);
      }
    }
  } else {
    bf16* dst = which ? Kw : Qw;
    const float scale = which ? 1.0f : 0.18033688011112042f;  // 0.125*log2(e)
    const float fexp = -2.0f * 13.287712379549449f / 64.0f;
#pragma unroll
    for (int i = 0; i < 2; ++i) {
      int dlo = i * 16 + col;
      float invf = exp2f(fexp * (float)dlo);
#pragma unroll
      for (int m = 0; m < 4; ++m) {
        int mg = m0 + wrow + m * 16 + g * 4;
        int b = mg >> 11;
        size_t rb = (size_t)(b * 16 + h) << 11;
#pragma unroll
        for (int r = 0; r < 4; ++r) {
          int s = (mg + r) & 2047;
          float sn, cs;
          __sincosf((float)s * invf, &sn, &cs);
          float lo = acc[m][i][r] * scale, hi = acc[m][i + 2][r] * scale;
          dst[((rb + s) << 6) + dlo] = __float2bfloat16(lo * cs - hi * sn);
          dst[((rb + s) << 6) + dlo + 32] = __float2bfloat16(hi * cs + lo * sn);
        }
      }
    }
  }
}

// ---------------------------------------------------------------- flash attention
// R10 structure + ones-column l: V LDS has rows 64..79 (row 64 = ones bf16,
// 65-79 = 0); PV's extra n2=4 MFMA accumulates o4 whose col-0 lanes hold
// l(q) = sum_keys P[key][q]. Removes the 16 l_s adds/tile + epilogue reduce.
__global__ __launch_bounds__(512) void k_attn(const bf16* __restrict__ Q,
                                              const bf16* __restrict__ K,
                                              const bf16* __restrict__ Vt,
                                              bf16* __restrict__ AO) {
  __shared__ bf16 QPl[128][72];  // Q staging, then P buffer (wave-private rows)
  __shared__ bf16 Kl[64][72];
  __shared__ bf16 Vl[80][72];  // [d][key]; rows 64..79 = ones/zeros block
  const int tid = threadIdx.x;
  const int wave = tid >> 6, lane = tid & 63, col = lane & 15, g = lane >> 4;
  const int bh = blockIdx.x;
  const size_t base = (size_t)bh << 17;
  const int r0 = tid >> 3, c0 = (tid & 7) * 8;  // r0: 0..63
  const int b = bh >> 4, h = bh & 15;
  // y -> qt mapping: quartets {y,y+4,y+8,y+12} sum to 30 => equal per-CU work
  const int yy = blockIdx.y, a = yy >> 2, r_ = yy & 3;
  const int qt = (a == 0) ? (15 - r_) : (a == 1) ? (8 + (r_ ^ 2)) : (a == 2) ? (4 + (r_ ^ 1)) : r_;
  const int q0 = qt * 128;
  // one-time: ones/zeros rows for the l-column MFMA (row 64 = 1.0, 65-79 = 0)
  if (tid < 144) {
    int4 v;
    if (tid < 9) {
      v.x = v.y = v.z = v.w = 0x3F803F80;  // bf16 1.0 pairs
    } else {
      v.x = v.y = v.z = v.w = 0;
    }
    reinterpret_cast<int4*>(&Vl[64][0])[tid] = v;
  }
  // stage Q tile
  *reinterpret_cast<int4*>(&QPl[r0][c0]) =
      *reinterpret_cast<const int4*>(&Q[base + (size_t)(q0 + r0) * 64 + c0]);
  *reinterpret_cast<int4*>(&QPl[r0 + 64][c0]) =
      *reinterpret_cast<const int4*>(&Q[base + (size_t)(q0 + r0 + 64) * 64 + c0]);
  const int ktlim = 2 * qt + 1;                  // block-wide last tile (incl.)
  const int ktmax = (q0 + wave * 16 + 15) >> 6;  // this wave's last useful tile
  // tile 0 -> LDS; tile 1 -> regs
  int4 kr = *reinterpret_cast<const int4*>(&K[base + (size_t)r0 * 64 + c0]);
  int4 vr = *reinterpret_cast<const int4*>(&Vt[base + (size_t)r0 * 2048 + c0]);
  *reinterpret_cast<int4*>(&Kl[r0][c0]) = kr;
  *reinterpret_cast<int4*>(&Vl[r0][c0]) = vr;
  kr = *reinterpret_cast<const int4*>(&K[base + (size_t)(64 + r0) * 64 + c0]);
  vr = *reinterpret_cast<const int4*>(&Vt[base + (size_t)r0 * 2048 + 64 + c0]);
  __syncthreads();
  bf16x8 qf[2];
#pragma unroll
  for (int kk = 0; kk < 2; ++kk)
    qf[kk] = *reinterpret_cast<const bf16x8*>(&QPl[wave * 16 + col][g * 8 + kk * 32]);
  f32x4 o[4] = {};
  f32x4 o4 = {};  // l accumulator (col 0 lanes)
  for (int kt = 0; kt <= ktlim; ++kt) {
    const int k0 = kt * 64;
    if (kt <= ktmax) {
      const int q = q0 + wave * 16 + col;
      const bool needmask = (k0 + 63 > q0 + wave * 16);  // wave-uniform
      __builtin_amdgcn_s_setprio(1);
#pragma unroll
      for (int n = 0; n < 4; ++n) {
        f32x4 s = {};
#pragma unroll
        for (int kk = 0; kk < 2; ++kk) {
          bf16x8 kf =
              *reinterpret_cast<const bf16x8*>(&Kl[n * 16 + col][g * 8 + kk * 32]);
          s = __builtin_amdgcn_mfma_f32_16x16x32_bf16(kf, qf[kk], s, 0, 0, 0);
        }
        if (needmask) {
#pragma unroll
          for (int r = 0; r < 4; ++r)
            if (k0 + n * 16 + g * 4 + r > q) s[r] = -3e38f;
        }
        alignas(8) bf16 t[4];
#pragma unroll
        for (int r = 0; r < 4; ++r) t[r] = __float2bfloat16(exp2f(s[r]));
        *reinterpret_cast<uint2*>(&QPl[wave * 16 + col][n * 16 + g * 4]) =
            *reinterpret_cast<uint2*>(t);
      }
      // O += P V ; o4 += P * ones  (P in wave-private LDS rows)
#pragma unroll
      for (int kk = 0; kk < 2; ++kk) {
        bf16x8 pf =
            *reinterpret_cast<const bf16x8*>(&QPl[wave * 16 + col][g * 8 + kk * 32]);
#pragma unroll
        for (int n2 = 0; n2 < 4; ++n2) {
          bf16x8 vf =
              *reinterpret_cast<const bf16x8*>(&Vl[n2 * 16 + col][g * 8 + kk * 32]);
          o[n2] = __builtin_amdgcn_mfma_f32_16x16x32_bf16(pf, vf, o[n2], 0, 0, 0);
        }
        bf16x8 vf4 =
            *reinterpret_cast<const bf16x8*>(&Vl[64 + col][g * 8 + kk * 32]);
        o4 = __builtin_amdgcn_mfma_f32_16x16x32_bf16(pf, vf4, o4, 0, 0, 0);
      }
      __builtin_amdgcn_s_setprio(0);
    }
    __syncthreads();  // all waves done reading Kl/Vl
    if (kt < ktlim) {
      *reinterpret_cast<int4*>(&Kl[r0][c0]) = kr;
      *reinterpret_cast<int4*>(&Vl[r0][c0]) = vr;
      if (kt + 2 <= ktlim) {
        const int k2 = k0 + 128;
        kr = *reinterpret_cast<const int4*>(&K[base + (size_t)(k2 + r0) * 64 + c0]);
        vr = *reinterpret_cast<const int4*>(&Vt[base + (size_t)r0 * 2048 + k2 + c0]);
      }
      __syncthreads();  // staged tile visible
    }
  }
  // epilogue: l(q=g*4+r) sits in o4[r] of the col-0 lane of each g-group
#pragma unroll
  for (int r = 0; r < 4; ++r) {
    float inv = 1.0f / __shfl(o4[r], lane & 48);
    int s = q0 + wave * 16 + g * 4 + r;
#pragma unroll
    for (int n2 = 0; n2 < 4; ++n2)
      AO[((size_t)(b * 2048 + s) << 10) + h * 64 + n2 * 16 + col] =
          __float2bfloat16(o[n2][r] * inv);
  }
}

// ---------------------------------------------------------------- out projection (R10: 128x128, BK=64, T2 swizzle)
__global__ __launch_bounds__(256) void k_outproj(const bf16* __restrict__ A,
                                                 const bf16* __restrict__ W,
                                                 float* __restrict__ OUT) {
  __shared__ bf16 Al[128 * 64];
  __shared__ bf16 Bl[128 * 64];
  const int tid = threadIdx.x;
  const int wave = tid >> 6, lane = tid & 63, col = lane & 15, g = lane >> 4;
  const int m0 = blockIdx.x * 128, n0 = blockIdx.y * 128;
  const int wrow = (wave >> 1) * 64, wcol = (wave & 1) * 64;
  const int row8 = tid >> 3;
  const int cel = ((tid & 7) * 8) ^ ((row8 & 7) * 8);
  const bf16* ga = A + (size_t)(m0 + row8) * 1024 + cel;
  const bf16* gb = W + (size_t)(n0 + row8) * 1024 + cel;
  bf16* la = Al + tid * 8;
  bf16* lb = Bl + tid * 8;
  const int rsw = (col & 7) * 8;
  f32x4 acc[4][4] = {};
  for (int k0 = 0; k0 < 1024; k0 += 64) {
    __syncthreads();
#pragma unroll
    for (int i = 0; i < 4; ++i) {
      gload16(ga + k0 + i * 32 * 1024, la + i * 2048);
      gload16(gb + k0 + i * 32 * 1024, lb + i * 2048);
    }
    __syncthreads();
#pragma unroll
    for (int kk = 0; kk < 2; ++kk) {
      const int ce = (kk * 32 + g * 8) ^ rsw;
      bf16x8 af[4], bfr[4];
#pragma unroll
      for (int m = 0; m < 4; ++m)
        af[m] = *reinterpret_cast<const bf16x8*>(&Al[(wrow + m * 16 + col) * 64 + ce]);
#pragma unroll
      for (int n = 0; n < 4; ++n)
        bfr[n] = *reinterpret_cast<const bf16x8*>(&Bl[(wcol + n * 16 + col) * 64 + ce]);
#pragma unroll
      for (int m = 0; m < 4; ++m)
#pragma unroll
        for (int n = 0; n < 4; ++n)
          acc[m][n] =
              __builtin_amdgcn_mfma_f32_16x16x32_bf16(af[m], bfr[n], acc[m][n], 0, 0, 0);
    }
  }
#pragma unroll
  for (int m = 0; m < 4; ++m)
#pragma unroll
    for (int n = 0; n < 4; ++n)
#pragma unroll
      for (int r = 0; r < 4; ++r)
        OUT[(size_t)(m0 + wrow + m * 16 + g * 4 + r) * 1024 + n0 + wcol + n * 16 + col] =
            acc[m][n][r];
}

// ---------------------------------------------------------------- launcher
extern "C" void kernel_launch(void* const* d_in, const int* in_sizes, int n_in,
                              void* d_out, int out_size, void* d_ws, size_t ws_size,
                              hipStream_t stream) {
  const float* x = (const float*)d_in[0];
  const float* wqkv = (const float*)d_in[1];
  const float* wout = (const float*)d_in[2];
  float* out = (float*)d_out;

  char* ws = (char*)d_ws;
  const size_t SZ_X = (size_t)B_ * S_ * D_ * 2;
  const size_t SZ_WQKV = (size_t)3 * D_ * D_ * 2;
  const size_t SZ_WOUT = (size_t)D_ * D_ * 2;
  const size_t SZ_T = (size_t)B_ * H_ * S_ * HD_ * 2;
  bf16* xb = (bf16*)(ws);
  bf16* wqkvb = (bf16*)(ws + SZ_X);
  bf16* woutb = (bf16*)(ws + SZ_X + SZ_WQKV);
  bf16* qws = (bf16*)(ws + SZ_X + SZ_WQKV + SZ_WOUT);
  bf16* kws = (bf16*)(ws + SZ_X + SZ_WQKV + SZ_WOUT + SZ_T);
  bf16* vtws = (bf16*)(ws + SZ_X + SZ_WQKV + SZ_WOUT + 2 * SZ_T);
  bf16* aob = (bf16*)(ws + SZ_X + SZ_WQKV + SZ_WOUT + 3 * SZ_T);

  const int NTOT4 = (NX_ + NW1_ + NW2_) / 4;
  k_cvt3<<<NTOT4 / 256, 256, 0, stream>>>(x, wqkv, wout, xb, wqkvb, woutb);

  k_qkv<<<dim3(64, 24), 256, 0, stream>>>(xb, wqkvb, qws, kws, vtws);
  k_attn<<<dim3(B_ * H_, 16), 512, 0, stream>>>(qws, kws, vtws, aob);
  k_outproj<<<dim3(64, 8), 256, 0, stream>>>(aob, woutb, out);
}

// Round 13
// 160.765 us; speedup vs baseline: 1.0965x; 1.0147x over previous
//
#include <hip/hip_runtime.h>
#include <hip/hip_bf16.h>

typedef __bf16 bf16x8 __attribute__((ext_vector_type(8)));
typedef float f32x4 __attribute__((ext_vector_type(4)));
typedef __hip_bfloat16 bf16;

#define B_ 4
#define S_ 2048
#define D_ 1024
#define H_ 16
#define HD_ 64

__device__ __forceinline__ void gload16(const bf16* g, bf16* l) {
  __builtin_amdgcn_global_load_lds(
      (const __attribute__((address_space(1))) unsigned int*)g,
      (__attribute__((address_space(3))) unsigned int*)l, 16, 0, 0);
}

#define MFMA16(a, b, c) __builtin_amdgcn_mfma_f32_16x16x32_bf16((a), (b), (c), 0, 0, 0)

// ---------------------------------------------------------------- cvt f32->bf16 (fused x, w_qkv, w_out)
#define NX_ (B_ * S_ * D_)
#define NW1_ (3 * D_ * D_)
#define NW2_ (D_ * D_)
__global__ __launch_bounds__(256) void k_cvt3(const float* __restrict__ x,
                                              const float* __restrict__ w1,
                                              const float* __restrict__ w2,
                                              bf16* __restrict__ ox,
                                              bf16* __restrict__ o1,
                                              bf16* __restrict__ o2) {
  int i = (blockIdx.x * 256 + threadIdx.x) * 4;
  const float* in;
  bf16* out;
  if (i < NX_) {
    in = x; out = ox;
  } else if (i < NX_ + NW1_) {
    in = w1; out = o1; i -= NX_;
  } else {
    in = w2; out = o2; i -= NX_ + NW1_;
  }
  float4 v = *reinterpret_cast<const float4*>(in + i);
  alignas(8) bf16 t[4];
  t[0] = __float2bfloat16(v.x);
  t[1] = __float2bfloat16(v.y);
  t[2] = __float2bfloat16(v.z);
  t[3] = __float2bfloat16(v.w);
  *reinterpret_cast<uint2*>(out + i) = *reinterpret_cast<uint2*>(t);
}

// ---------------------------------------------------------------- QKV GEMM
// BM=128 x BN=256, BK=64, 512 thr (8 waves 2Mx4N, per-wave 64x64).
// Interleaved counted-vmcnt loop (m201-style): hoist ALL frag ds_reads to
// phase 0; first MFMA cluster overlaps trailing reads; lgkmcnt(0)+barrier
// frees buf; stage-issues for kt+2 interleaved between register-only MFMA
// clusters; vmcnt(6) (never 0) in main loop. Both-sides XOR swizzle (R10).
// Grid 64x12 = 768 = 3 exact rounds at 96KB LDS (1 block/CU).
__global__ __launch_bounds__(512) void k_qkv(const bf16* __restrict__ X,
                                             const bf16* __restrict__ W,
                                             bf16* __restrict__ Qw,
                                             bf16* __restrict__ Kw,
                                             bf16* __restrict__ Vtw) {
  __shared__ bf16 Al[2][128 * 64];  // 32 KB
  __shared__ bf16 Bl[2][256 * 64];  // 64 KB
  const int tid = threadIdx.x;
  const int wid = tid >> 6, lane = tid & 63, col = lane & 15, g = lane >> 4;
  const int wr = wid >> 2, wc = wid & 3;
  const int m0 = blockIdx.x * 128, n0 = blockIdx.y * 256;
  const int srow = tid >> 3;                 // 0..63
  const int scol = (tid & 7) * 8;
  const int csrc = scol ^ ((srow & 7) * 8);  // pre-swizzled source col
  const bf16* ga = X + (size_t)(m0 + srow) * 1024 + csrc;
  const bf16* gb = W + (size_t)(n0 + srow) * 1024 + csrc;
  const int ldst = srow * 64 + scol;         // linear LDS dest
  const int rsw = (col & 7) * 8;
  f32x4 acc[4][4] = {};
#define QKV_STAGE_ALL(buf, k0)                               \
  do {                                                       \
    gload16(ga + (k0), &Al[buf][ldst]);                      \
    gload16(ga + (k0) + 64 * 1024, &Al[buf][ldst + 4096]);   \
    gload16(gb + (k0), &Bl[buf][ldst]);                      \
    gload16(gb + (k0) + 64 * 1024, &Bl[buf][ldst + 4096]);   \
    gload16(gb + (k0) + 128 * 1024, &Bl[buf][ldst + 8192]);  \
    gload16(gb + (k0) + 192 * 1024, &Bl[buf][ldst + 12288]); \
  } while (0)
  QKV_STAGE_ALL(0, 0);
  QKV_STAGE_ALL(1, 64);
  for (int kt = 0; kt < 16; ++kt) {
    const int c = kt & 1;
    if (kt < 15)
      asm volatile("s_waitcnt vmcnt(6)" ::: "memory");
    else
      asm volatile("s_waitcnt vmcnt(0)" ::: "memory");
    __builtin_amdgcn_s_barrier();  // tile kt landed for all waves
    const bf16* Ac = Al[c];
    const bf16* Bc = Bl[c];
    // phase 0: ALL frag reads for this K-tile
    bf16x8 af[2][4], bfr[2][4];
#pragma unroll
    for (int kk = 0; kk < 2; ++kk) {
      const int ce = (kk * 32 + g * 8) ^ rsw;
#pragma unroll
      for (int m = 0; m < 4; ++m)
        af[kk][m] =
            *reinterpret_cast<const bf16x8*>(&Ac[(wr * 64 + m * 16 + col) * 64 + ce]);
#pragma unroll
      for (int n = 0; n < 4; ++n)
        bfr[kk][n] =
            *reinterpret_cast<const bf16x8*>(&Bc[(wc * 64 + n * 16 + col) * 64 + ce]);
    }
    // cluster 1 overlaps trailing ds_reads
    __builtin_amdgcn_s_setprio(1);
#pragma unroll
    for (int m = 0; m < 4; ++m) {
      acc[m][0] = MFMA16(af[0][m], bfr[0][0], acc[m][0]);
      acc[m][1] = MFMA16(af[0][m], bfr[0][1], acc[m][1]);
    }
    __builtin_amdgcn_s_setprio(0);
    asm volatile("s_waitcnt lgkmcnt(0)" ::: "memory");
    __builtin_amdgcn_sched_barrier(0);
    __builtin_amdgcn_s_barrier();  // all waves' reads of buf c complete -> free
    const bool more = (kt + 2 < 16);
    const int k2 = (kt + 2) * 64;
    if (more) {
      gload16(ga + k2, &Al[c][ldst]);
      gload16(ga + k2 + 64 * 1024, &Al[c][ldst + 4096]);
    }
    __builtin_amdgcn_s_setprio(1);
#pragma unroll
    for (int m = 0; m < 4; ++m) {
      acc[m][2] = MFMA16(af[0][m], bfr[0][2], acc[m][2]);
      acc[m][3] = MFMA16(af[0][m], bfr[0][3], acc[m][3]);
    }
    __builtin_amdgcn_s_setprio(0);
    if (more) {
      gload16(gb + k2, &Bl[c][ldst]);
      gload16(gb + k2 + 64 * 1024, &Bl[c][ldst + 4096]);
    }
    __builtin_amdgcn_s_setprio(1);
#pragma unroll
    for (int m = 0; m < 4; ++m) {
      acc[m][0] = MFMA16(af[1][m], bfr[1][0], acc[m][0]);
      acc[m][1] = MFMA16(af[1][m], bfr[1][1], acc[m][1]);
    }
    __builtin_amdgcn_s_setprio(0);
    if (more) {
      gload16(gb + k2 + 128 * 1024, &Bl[c][ldst + 8192]);
      gload16(gb + k2 + 192 * 1024, &Bl[c][ldst + 12288]);
    }
    __builtin_amdgcn_s_setprio(1);
#pragma unroll
    for (int m = 0; m < 4; ++m) {
      acc[m][2] = MFMA16(af[1][m], bfr[1][2], acc[m][2]);
      acc[m][3] = MFMA16(af[1][m], bfr[1][3], acc[m][3]);
    }
    __builtin_amdgcn_s_setprio(0);
  }
#undef QKV_STAGE_ALL
  const int e0 = n0 + wc * 64;
  const int which = e0 >> 10;
  const int h = (e0 >> 6) & 15;
  if (which == 2) {
#pragma unroll
    for (int m = 0; m < 4; ++m) {
      int mg = m0 + wr * 64 + m * 16 + g * 4;
      int b = mg >> 11, s = mg & 2047;
#pragma unroll
      for (int n = 0; n < 4; ++n) {
        int d = n * 16 + col;
        alignas(8) bf16 t[4];
#pragma unroll
        for (int r = 0; r < 4; ++r) t[r] = __float2bfloat16(acc[m][n][r]);
        *reinterpret_cast<uint2*>(&Vtw[((size_t)((b * 16 + h) * 64 + d) << 11) + s]) =
            *reinterpret_cast<uint2*>(t);
      }
    }
  } else {
    bf16* dst = which ? Kw : Qw;
    const float scale = which ? 1.0f : 0.18033688011112042f;  // 0.125*log2(e)
    const float fexp = -2.0f * 13.287712379549449f / 64.0f;
#pragma unroll
    for (int i = 0; i < 2; ++i) {
      int dlo = i * 16 + col;
      float invf = exp2f(fexp * (float)dlo);
#pragma unroll
      for (int m = 0; m < 4; ++m) {
        int mg = m0 + wr * 64 + m * 16 + g * 4;
        int b = mg >> 11;
        size_t rb = (size_t)(b * 16 + h) << 11;
#pragma unroll
        for (int r = 0; r < 4; ++r) {
          int s = (mg + r) & 2047;
          float sn, cs;
          __sincosf((float)s * invf, &sn, &cs);
          float lo = acc[m][i][r] * scale, hi = acc[m][i + 2][r] * scale;
          dst[((rb + s) << 6) + dlo] = __float2bfloat16(lo * cs - hi * sn);
          dst[((rb + s) << 6) + dlo + 32] = __float2bfloat16(hi * cs + lo * sn);
        }
      }
    }
  }
}

// ---------------------------------------------------------------- flash attention (R10, reverted)
// QBLK=128, 512 threads: 8 waves x 16 q-rows. KVBLK=64. Swapped QK^T (lane
// owns q=col). No-max softmax (exp2 domain); l reduced cross-lane once in
// epilogue. QTMAP balances CU quartets. Single-buffer K/V LDS -> 4 blocks/CU.
__global__ __launch_bounds__(512) void k_attn(const bf16* __restrict__ Q,
                                              const bf16* __restrict__ K,
                                              const bf16* __restrict__ Vt,
                                              bf16* __restrict__ AO) {
  __shared__ bf16 QPl[128][72];  // Q staging, then P buffer (wave-private rows)
  __shared__ bf16 Kl[64][72];
  __shared__ bf16 Vl[64][72];  // [d][key]
  const int tid = threadIdx.x;
  const int wave = tid >> 6, lane = tid & 63, col = lane & 15, g = lane >> 4;
  const int bh = blockIdx.x;
  const size_t base = (size_t)bh << 17;
  const int r0 = tid >> 3, c0 = (tid & 7) * 8;  // r0: 0..63
  const int b = bh >> 4, h = bh & 15;
  // y -> qt mapping: quartets {y,y+4,y+8,y+12} sum to 30 => equal per-CU work
  const int yy = blockIdx.y, a = yy >> 2, r_ = yy & 3;
  const int qt = (a == 0) ? (15 - r_) : (a == 1) ? (8 + (r_ ^ 2)) : (a == 2) ? (4 + (r_ ^ 1)) : r_;
  const int q0 = qt * 128;
  *reinterpret_cast<int4*>(&QPl[r0][c0]) =
      *reinterpret_cast<const int4*>(&Q[base + (size_t)(q0 + r0) * 64 + c0]);
  *reinterpret_cast<int4*>(&QPl[r0 + 64][c0]) =
      *reinterpret_cast<const int4*>(&Q[base + (size_t)(q0 + r0 + 64) * 64 + c0]);
  const int ktlim = 2 * qt + 1;                  // block-wide last tile (incl.)
  const int ktmax = (q0 + wave * 16 + 15) >> 6;  // this wave's last useful tile
  int4 kr = *reinterpret_cast<const int4*>(&K[base + (size_t)r0 * 64 + c0]);
  int4 vr = *reinterpret_cast<const int4*>(&Vt[base + (size_t)r0 * 2048 + c0]);
  *reinterpret_cast<int4*>(&Kl[r0][c0]) = kr;
  *reinterpret_cast<int4*>(&Vl[r0][c0]) = vr;
  kr = *reinterpret_cast<const int4*>(&K[base + (size_t)(64 + r0) * 64 + c0]);
  vr = *reinterpret_cast<const int4*>(&Vt[base + (size_t)r0 * 2048 + 64 + c0]);
  __syncthreads();
  bf16x8 qf[2];
#pragma unroll
  for (int kk = 0; kk < 2; ++kk)
    qf[kk] = *reinterpret_cast<const bf16x8*>(&QPl[wave * 16 + col][g * 8 + kk * 32]);
  float l_s = 0.0f;
  f32x4 o[4] = {};
  for (int kt = 0; kt <= ktlim; ++kt) {
    const int k0 = kt * 64;
    if (kt <= ktmax) {
      const int q = q0 + wave * 16 + col;
      const bool needmask = (k0 + 63 > q0 + wave * 16);  // wave-uniform
      __builtin_amdgcn_s_setprio(1);
#pragma unroll
      for (int n = 0; n < 4; ++n) {
        f32x4 s = {};
#pragma unroll
        for (int kk = 0; kk < 2; ++kk) {
          bf16x8 kf =
              *reinterpret_cast<const bf16x8*>(&Kl[n * 16 + col][g * 8 + kk * 32]);
          s = MFMA16(kf, qf[kk], s);
        }
        if (needmask) {
#pragma unroll
          for (int r = 0; r < 4; ++r)
            if (k0 + n * 16 + g * 4 + r > q) s[r] = -3e38f;
        }
        alignas(8) bf16 t[4];
#pragma unroll
        for (int r = 0; r < 4; ++r) {
          float p = exp2f(s[r]);
          l_s += p;
          t[r] = __float2bfloat16(p);
        }
        *reinterpret_cast<uint2*>(&QPl[wave * 16 + col][n * 16 + g * 4]) =
            *reinterpret_cast<uint2*>(t);
      }
      // O += P V   (P in wave-private LDS rows)
#pragma unroll
      for (int kk = 0; kk < 2; ++kk) {
        bf16x8 pf =
            *reinterpret_cast<const bf16x8*>(&QPl[wave * 16 + col][g * 8 + kk * 32]);
#pragma unroll
        for (int n2 = 0; n2 < 4; ++n2) {
          bf16x8 vf =
              *reinterpret_cast<const bf16x8*>(&Vl[n2 * 16 + col][g * 8 + kk * 32]);
          o[n2] = MFMA16(pf, vf, o[n2]);
        }
      }
      __builtin_amdgcn_s_setprio(0);
    }
    __syncthreads();  // all waves done reading Kl/Vl
    if (kt < ktlim) {
      *reinterpret_cast<int4*>(&Kl[r0][c0]) = kr;
      *reinterpret_cast<int4*>(&Vl[r0][c0]) = vr;
      if (kt + 2 <= ktlim) {
        const int k2 = k0 + 128;
        kr = *reinterpret_cast<const int4*>(&K[base + (size_t)(k2 + r0) * 64 + c0]);
        vr = *reinterpret_cast<const int4*>(&Vt[base + (size_t)r0 * 2048 + k2 + c0]);
      }
      __syncthreads();  // staged tile visible
    }
  }
  l_s += __shfl_xor(l_s, 16);
  l_s += __shfl_xor(l_s, 32);
#pragma unroll
  for (int r = 0; r < 4; ++r) {
    float inv = 1.0f / __shfl(l_s, (lane & 48) | (g * 4 + r));
    int s = q0 + wave * 16 + g * 4 + r;
#pragma unroll
    for (int n2 = 0; n2 < 4; ++n2)
      AO[((size_t)(b * 2048 + s) << 10) + h * 64 + n2 * 16 + col] =
          __float2bfloat16(o[n2][r] * inv);
  }
}

// ---------------------------------------------------------------- out projection
// Same interleaved counted-vmcnt template. Grid 64x4 = 256 blocks = 1 round.
__global__ __launch_bounds__(512) void k_outproj(const bf16* __restrict__ A,
                                                 const bf16* __restrict__ W,
                                                 float* __restrict__ OUT) {
  __shared__ bf16 Al[2][128 * 64];
  __shared__ bf16 Bl[2][256 * 64];
  const int tid = threadIdx.x;
  const int wid = tid >> 6, lane = tid & 63, col = lane & 15, g = lane >> 4;
  const int wr = wid >> 2, wc = wid & 3;
  const int m0 = blockIdx.x * 128, n0 = blockIdx.y * 256;
  const int srow = tid >> 3;
  const int scol = (tid & 7) * 8;
  const int csrc = scol ^ ((srow & 7) * 8);
  const bf16* ga = A + (size_t)(m0 + srow) * 1024 + csrc;
  const bf16* gb = W + (size_t)(n0 + srow) * 1024 + csrc;
  const int ldst = srow * 64 + scol;
  const int rsw = (col & 7) * 8;
  f32x4 acc[4][4] = {};
#define OP_STAGE_ALL(buf, k0)                                \
  do {                                                       \
    gload16(ga + (k0), &Al[buf][ldst]);                      \
    gload16(ga + (k0) + 64 * 1024, &Al[buf][ldst + 4096]);   \
    gload16(gb + (k0), &Bl[buf][ldst]);                      \
    gload16(gb + (k0) + 64 * 1024, &Bl[buf][ldst + 4096]);   \
    gload16(gb + (k0) + 128 * 1024, &Bl[buf][ldst + 8192]);  \
    gload16(gb + (k0) + 192 * 1024, &Bl[buf][ldst + 12288]); \
  } while (0)
  OP_STAGE_ALL(0, 0);
  OP_STAGE_ALL(1, 64);
  for (int kt = 0; kt < 16; ++kt) {
    const int c = kt & 1;
    if (kt < 15)
      asm volatile("s_waitcnt vmcnt(6)" ::: "memory");
    else
      asm volatile("s_waitcnt vmcnt(0)" ::: "memory");
    __builtin_amdgcn_s_barrier();
    const bf16* Ac = Al[c];
    const bf16* Bc = Bl[c];
    bf16x8 af[2][4], bfr[2][4];
#pragma unroll
    for (int kk = 0; kk < 2; ++kk) {
      const int ce = (kk * 32 + g * 8) ^ rsw;
#pragma unroll
      for (int m = 0; m < 4; ++m)
        af[kk][m] =
            *reinterpret_cast<const bf16x8*>(&Ac[(wr * 64 + m * 16 + col) * 64 + ce]);
#pragma unroll
      for (int n = 0; n < 4; ++n)
        bfr[kk][n] =
            *reinterpret_cast<const bf16x8*>(&Bc[(wc * 64 + n * 16 + col) * 64 + ce]);
    }
    __builtin_amdgcn_s_setprio(1);
#pragma unroll
    for (int m = 0; m < 4; ++m) {
      acc[m][0] = MFMA16(af[0][m], bfr[0][0], acc[m][0]);
      acc[m][1] = MFMA16(af[0][m], bfr[0][1], acc[m][1]);
    }
    __builtin_amdgcn_s_setprio(0);
    asm volatile("s_waitcnt lgkmcnt(0)" ::: "memory");
    __builtin_amdgcn_sched_barrier(0);
    __builtin_amdgcn_s_barrier();
    const bool more = (kt + 2 < 16);
    const int k2 = (kt + 2) * 64;
    if (more) {
      gload16(ga + k2, &Al[c][ldst]);
      gload16(ga + k2 + 64 * 1024, &Al[c][ldst + 4096]);
    }
    __builtin_amdgcn_s_setprio(1);
#pragma unroll
    for (int m = 0; m < 4; ++m) {
      acc[m][2] = MFMA16(af[0][m], bfr[0][2], acc[m][2]);
      acc[m][3] = MFMA16(af[0][m], bfr[0][3], acc[m][3]);
    }
    __builtin_amdgcn_s_setprio(0);
    if (more) {
      gload16(gb + k2, &Bl[c][ldst]);
      gload16(gb + k2 + 64 * 1024, &Bl[c][ldst + 4096]);
    }
    __builtin_amdgcn_s_setprio(1);
#pragma unroll
    for (int m = 0; m < 4; ++m) {
      acc[m][0] = MFMA16(af[1][m], bfr[1][0], acc[m][0]);
      acc[m][1] = MFMA16(af[1][m], bfr[1][1], acc[m][1]);
    }
    __builtin_amdgcn_s_setprio(0);
    if (more) {
      gload16(gb + k2 + 128 * 1024, &Bl[c][ldst + 8192]);
      gload16(gb + k2 + 192 * 1024, &Bl[c][ldst + 12288]);
    }
    __builtin_amdgcn_s_setprio(1);
#pragma unroll
    for (int m = 0; m < 4; ++m) {
      acc[m][2] = MFMA16(af[1][m], bfr[1][2], acc[m][2]);
      acc[m][3] = MFMA16(af[1][m], bfr[1][3], acc[m][3]);
    }
    __builtin_amdgcn_s_setprio(0);
  }
#undef OP_STAGE_ALL
#pragma unroll
  for (int m = 0; m < 4; ++m)
#pragma unroll
    for (int n = 0; n < 4; ++n)
#pragma unroll
      for (int r = 0; r < 4; ++r)
        OUT[(size_t)(m0 + wr * 64 + m * 16 + g * 4 + r) * 1024 + n0 + wc * 64 + n * 16 +
            col] = acc[m][n][r];
}

// ---------------------------------------------------------------- launcher
extern "C" void kernel_launch(void* const* d_in, const int* in_sizes, int n_in,
                              void* d_out, int out_size, void* d_ws, size_t ws_size,
                              hipStream_t stream) {
  const float* x = (const float*)d_in[0];
  const float* wqkv = (const float*)d_in[1];
  const float* wout = (const float*)d_in[2];
  float* out = (float*)d_out;

  char* ws = (char*)d_ws;
  const size_t SZ_X = (size_t)B_ * S_ * D_ * 2;
  const size_t SZ_WQKV = (size_t)3 * D_ * D_ * 2;
  const size_t SZ_WOUT = (size_t)D_ * D_ * 2;
  const size_t SZ_T = (size_t)B_ * H_ * S_ * HD_ * 2;
  bf16* xb = (bf16*)(ws);
  bf16* wqkvb = (bf16*)(ws + SZ_X);
  bf16* woutb = (bf16*)(ws + SZ_X + SZ_WQKV);
  bf16* qws = (bf16*)(ws + SZ_X + SZ_WQKV + SZ_WOUT);
  bf16* kws = (bf16*)(ws + SZ_X + SZ_WQKV + SZ_WOUT + SZ_T);
  bf16* vtws = (bf16*)(ws + SZ_X + SZ_WQKV + SZ_WOUT + 2 * SZ_T);
  bf16* aob = (bf16*)(ws + SZ_X + SZ_WQKV + SZ_WOUT + 3 * SZ_T);

  const int NTOT4 = (NX_ + NW1_ + NW2_) / 4;
  k_cvt3<<<NTOT4 / 256, 256, 0, stream>>>(x, wqkv, wout, xb, wqkvb, woutb);

  k_qkv<<<dim3(64, 12), 512, 0, stream>>>(xb, wqkvb, qws, kws, vtws);
  k_attn<<<dim3(B_ * H_, 16), 512, 0, stream>>>(qws, kws, vtws, aob);
  k_outproj<<<dim3(64, 4), 512, 0, stream>>>(aob, woutb, out);
}